// Round 1
// baseline (1565.102 us; speedup 1.0000x reference)
//
#include <hip/hip_runtime.h>

// MetaPathGNN — only the edge2 (B->C) layer + output GEMM matter
// (h_B is dead code in the reference).
//
// Pipeline:
//   memset  : zero agg/deg/cnt in ws
//   K1      : per-edge gather x_B[s]*w, atomic scatter-add into agg[d], deg, cnt
//   K2      : out = agg/deg; y = out@Wl + x_C@Wcomb + bc; relu; LN; select -> hC
//   K3      : d_out = hC @ Wout + bout
//
// ws layout (floats): [agg N*128 | deg N | cnt N | hC N*128]  (~103 MB)

#define HD 128
#define OD 64

__device__ __forceinline__ float softplus_f(float x) {
    return fmaxf(x, 0.0f) + log1pf(expf(-fabsf(x)));
}
__device__ __forceinline__ float sigmoid_f(float x) {
    return 1.0f / (1.0f + expf(-x));
}

// ---------------------------------------------------------------- K1: scatter
// one 32-lane group per edge; lane handles 4 consecutive columns (float4 load)
__global__ __launch_bounds__(256) void k_edge_scatter(
    const float* __restrict__ xB, const float* __restrict__ tB,
    const float* __restrict__ tC, const int* __restrict__ edge,
    const float* __restrict__ lam_raw,
    float* __restrict__ agg, float* __restrict__ deg, int* __restrict__ cnt,
    int E)
{
    int gid  = blockIdx.x * 256 + threadIdx.x;
    int e    = gid >> 5;
    int lane = gid & 31;
    if (e >= E) return;

    int s = edge[e];
    int d = edge[E + e];

    float lam   = softplus_f(lam_raw[0]) + 1e-8f;
    float delta = fmaxf(tC[d] - tB[s], 0.0f);
    float w     = expf(fmaxf(-lam * delta, -60.0f));

    const float4 x = *reinterpret_cast<const float4*>(xB + (size_t)s * HD + lane * 4);
    float* dst = agg + (size_t)d * HD + lane * 4;
    unsafeAtomicAdd(dst + 0, x.x * w);
    unsafeAtomicAdd(dst + 1, x.y * w);
    unsafeAtomicAdd(dst + 2, x.z * w);
    unsafeAtomicAdd(dst + 3, x.w * w);
    if (lane == 0) {
        unsafeAtomicAdd(deg + d, w);
        atomicAdd(cnt + d, 1);
    }
}

// ---------------------------------------------------------------- K2: layer
// block = 256 thr, tile = 32 rows x 128 cols, K=256 (A1=agg/deg, A2=x_C)
// 4 phases: (Wl,A1,kh0) (Wl,A1,kh1) (Wc,A2,kh0) (Wc,A2,kh1); acc persists.
__global__ __launch_bounds__(256) void k_layer(
    const float* __restrict__ xC, const float* __restrict__ agg,
    const float* __restrict__ deg, const int* __restrict__ cnt,
    const float* __restrict__ Wl, const float* __restrict__ W0,
    const float* __restrict__ W1, const float* __restrict__ bl,
    const float* __restrict__ b0, const float* __restrict__ b1,
    const float* __restrict__ gatep, const float* __restrict__ lng,
    const float* __restrict__ lnb, float* __restrict__ hC, int N)
{
    __shared__ float Bs[64][128];   // 32 KB: weight K-half
    __shared__ float As[64][36];    // 9 KB : A-tile transposed [k][row], padded

    const int t     = threadIdx.x;
    const int cg    = t & 31;       // col group: cols cg*4..+3
    const int rg    = t >> 5;       // row group: rows rg*4..+3 (0..7)
    const int rbase = blockIdx.x * 32;
    const float g   = sigmoid_f(gatep[0]);

    float acc[4][4] = {};

    for (int ph = 0; ph < 4; ++ph) {
        const int mat = ph >> 1;    // 0: Wl vs A1, 1: Wcomb vs A2(x_C)
        const int kh  = ph & 1;     // K half

        // ---- stage B half (64x128), flat coalesced float4
        {
            const float* src0 = (mat == 0) ? Wl : W0;
#pragma unroll
            for (int i = 0; i < 8; ++i) {
                int f = t * 4 + i * 1024;
                float4 v = *reinterpret_cast<const float4*>(src0 + kh * 8192 + f);
                if (mat == 1) {
                    float4 v1 = *reinterpret_cast<const float4*>(W1 + kh * 8192 + f);
                    v.x = (1.f - g) * v.x + g * v1.x;
                    v.y = (1.f - g) * v.y + g * v1.y;
                    v.z = (1.f - g) * v.z + g * v1.z;
                    v.w = (1.f - g) * v.w + g * v1.w;
                }
                *reinterpret_cast<float4*>(&Bs[0][0] + f) = v;
            }
        }
        // ---- stage A half transposed: As[k][row]
        {
            const int rl = t & 31;
            const int k0 = (t >> 5) * 8;
            const int r  = rbase + rl;
            float av[8];
            if (r < N) {
                const float* src = (mat == 0) ? agg : xC;
                float4 u0 = *reinterpret_cast<const float4*>(src + (size_t)r * HD + kh * 64 + k0);
                float4 u1 = *reinterpret_cast<const float4*>(src + (size_t)r * HD + kh * 64 + k0 + 4);
                float sc = 1.0f;
                if (mat == 0) sc = 1.0f / fmaxf(deg[r], 1e-6f);
                av[0] = u0.x * sc; av[1] = u0.y * sc; av[2] = u0.z * sc; av[3] = u0.w * sc;
                av[4] = u1.x * sc; av[5] = u1.y * sc; av[6] = u1.z * sc; av[7] = u1.w * sc;
            } else {
#pragma unroll
                for (int j = 0; j < 8; ++j) av[j] = 0.0f;
            }
#pragma unroll
            for (int j = 0; j < 8; ++j) As[k0 + j][rl] = av[j];   // conflict-free
        }
        __syncthreads();

#pragma unroll 4
        for (int k = 0; k < 64; ++k) {
            float4 a4 = *reinterpret_cast<const float4*>(&As[k][rg * 4]);
            float4 b4 = *reinterpret_cast<const float4*>(&Bs[k][cg * 4]);
            const float aa[4] = {a4.x, a4.y, a4.z, a4.w};
            const float bb[4] = {b4.x, b4.y, b4.z, b4.w};
#pragma unroll
            for (int i = 0; i < 4; ++i)
#pragma unroll
                for (int j = 0; j < 4; ++j)
                    acc[i][j] = fmaf(aa[i], bb[j], acc[i][j]);
        }
        __syncthreads();
    }

    // ---- epilogue: bias, relu, LN (row reduce over the 32-thread col group)
    float4 blv = *reinterpret_cast<const float4*>(bl + cg * 4);
    float4 b0v = *reinterpret_cast<const float4*>(b0 + cg * 4);
    float4 b1v = *reinterpret_cast<const float4*>(b1 + cg * 4);
    const float bc[4] = {
        blv.x + (1.f - g) * b0v.x + g * b1v.x,
        blv.y + (1.f - g) * b0v.y + g * b1v.y,
        blv.z + (1.f - g) * b0v.z + g * b1v.z,
        blv.w + (1.f - g) * b0v.w + g * b1v.w};
    float4 lngv = *reinterpret_cast<const float4*>(lng + cg * 4);
    float4 lnbv = *reinterpret_cast<const float4*>(lnb + cg * 4);
    const float ga[4] = {lngv.x, lngv.y, lngv.z, lngv.w};
    const float be[4] = {lnbv.x, lnbv.y, lnbv.z, lnbv.w};

#pragma unroll
    for (int i = 0; i < 4; ++i) {
        float y[4], s = 0.f, q = 0.f;
#pragma unroll
        for (int j = 0; j < 4; ++j) {
            float v = fmaxf(acc[i][j] + bc[j], 0.0f);
            y[j] = v; s += v; q += v * v;
        }
        // reduce across the 32 threads holding this row (half-wave groups)
#pragma unroll
        for (int m = 1; m < 32; m <<= 1) {
            s += __shfl_xor(s, m);
            q += __shfl_xor(q, m);
        }
        float mu   = s * (1.0f / 128.0f);
        float var  = q * (1.0f / 128.0f) - mu * mu;
        float rstd = rsqrtf(var + 1e-5f);

        int r = rbase + rg * 4 + i;
        if (r < N) {
            float4 res;
            if (cnt[r] > 0) {
                res.x = (y[0] - mu) * rstd * ga[0] + be[0];
                res.y = (y[1] - mu) * rstd * ga[1] + be[1];
                res.z = (y[2] - mu) * rstd * ga[2] + be[2];
                res.w = (y[3] - mu) * rstd * ga[3] + be[3];
            } else {
                res = *reinterpret_cast<const float4*>(xC + (size_t)r * HD + cg * 4);
            }
            *reinterpret_cast<float4*>(hC + (size_t)r * HD + cg * 4) = res;
        }
    }
}

// ---------------------------------------------------------------- K3: out GEMM
// block = 256 thr, tile = 32 rows x 64 cols, K=128
__global__ __launch_bounds__(256) void k_out(
    const float* __restrict__ hC, const float* __restrict__ Wout,
    const float* __restrict__ bout, float* __restrict__ out, int N)
{
    __shared__ float Bs[128][64];   // 32 KB Wout
    __shared__ float As[128][36];   // 18 KB A-tile transposed, padded

    const int t     = threadIdx.x;
    const int rbase = blockIdx.x * 32;

    // stage B (8192 floats, flat)
#pragma unroll
    for (int i = 0; i < 8; ++i) {
        int f = t * 4 + i * 1024;
        *reinterpret_cast<float4*>(&Bs[0][0] + f) =
            *reinterpret_cast<const float4*>(Wout + f);
    }
    // stage A transposed
    {
        const int rl = t & 31;
        const int k0 = (t >> 5) * 16;
        const int r  = rbase + rl;
        float av[16];
        if (r < N) {
#pragma unroll
            for (int c = 0; c < 4; ++c) {
                float4 u = *reinterpret_cast<const float4*>(hC + (size_t)r * HD + k0 + c * 4);
                av[c * 4 + 0] = u.x; av[c * 4 + 1] = u.y;
                av[c * 4 + 2] = u.z; av[c * 4 + 3] = u.w;
            }
        } else {
#pragma unroll
            for (int j = 0; j < 16; ++j) av[j] = 0.0f;
        }
#pragma unroll
        for (int j = 0; j < 16; ++j) As[k0 + j][rl] = av[j];   // conflict-free
    }
    __syncthreads();

    const int cg = t & 15;   // cols cg*4..+3
    const int rg = t >> 4;   // rows rg*2..+1 (0..15)
    float acc[2][4] = {};

#pragma unroll 4
    for (int k = 0; k < 128; ++k) {
        float2 a2 = *reinterpret_cast<const float2*>(&As[k][rg * 2]);
        float4 b4 = *reinterpret_cast<const float4*>(&Bs[k][cg * 4]);
        acc[0][0] = fmaf(a2.x, b4.x, acc[0][0]);
        acc[0][1] = fmaf(a2.x, b4.y, acc[0][1]);
        acc[0][2] = fmaf(a2.x, b4.z, acc[0][2]);
        acc[0][3] = fmaf(a2.x, b4.w, acc[0][3]);
        acc[1][0] = fmaf(a2.y, b4.x, acc[1][0]);
        acc[1][1] = fmaf(a2.y, b4.y, acc[1][1]);
        acc[1][2] = fmaf(a2.y, b4.z, acc[1][2]);
        acc[1][3] = fmaf(a2.y, b4.w, acc[1][3]);
    }

    float4 bo = *reinterpret_cast<const float4*>(bout + cg * 4);
#pragma unroll
    for (int i = 0; i < 2; ++i) {
        int r = rbase + rg * 2 + i;
        if (r < N) {
            float4 res;
            res.x = acc[i][0] + bo.x;
            res.y = acc[i][1] + bo.y;
            res.z = acc[i][2] + bo.z;
            res.w = acc[i][3] + bo.w;
            *reinterpret_cast<float4*>(out + (size_t)r * OD + cg * 4) = res;
        }
    }
}

// ---------------------------------------------------------------- launch
extern "C" void kernel_launch(void* const* d_in, const int* in_sizes, int n_in,
                              void* d_out, int out_size, void* d_ws, size_t ws_size,
                              hipStream_t stream) {
    const float* xB    = (const float*)d_in[1];
    const float* xC    = (const float*)d_in[2];
    const float* tB    = (const float*)d_in[4];
    const float* tC    = (const float*)d_in[5];
    const int*   edge2 = (const int*)d_in[7];
    const float* Wl1   = (const float*)d_in[18];
    const float* bl1   = (const float*)d_in[19];
    const float* W01   = (const float*)d_in[20];
    const float* b01   = (const float*)d_in[21];
    const float* W11   = (const float*)d_in[22];
    const float* b11   = (const float*)d_in[23];
    const float* gate1 = (const float*)d_in[24];
    const float* lam1  = (const float*)d_in[25];
    const float* lng1  = (const float*)d_in[26];
    const float* lnb1  = (const float*)d_in[27];
    const float* Wout  = (const float*)d_in[28];
    const float* bout  = (const float*)d_in[29];

    const int N = in_sizes[2] / HD;
    const int E = in_sizes[7] / 2;

    float* agg = (float*)d_ws;
    float* deg = agg + (size_t)N * HD;
    int*   cnt = (int*)(deg + N);
    float* hC  = (float*)(cnt + N);

    // zero agg | deg | cnt (contiguous)
    hipMemsetAsync(agg, 0, (size_t)N * (HD + 2) * sizeof(float), stream);

    dim3 blk(256);
    int g1 = (int)(((long long)E * 32 + 255) / 256);
    k_edge_scatter<<<g1, blk, 0, stream>>>(xB, tB, tC, edge2, lam1, agg, deg, cnt, E);

    int g2 = (N + 31) / 32;
    k_layer<<<g2, blk, 0, stream>>>(xC, agg, deg, cnt, Wl1, W01, W11,
                                    bl1, b01, b11, gate1, lng1, lnb1, hC, N);

    int g3 = (N + 31) / 32;
    k_out<<<g3, blk, 0, stream>>>(hC, Wout, bout, (float*)d_out, N);
}

// Round 2
// 327.524 us; speedup vs baseline: 4.7786x; 4.7786x over previous
//
#include <hip/hip_runtime.h>

// MetaPathGNN — only the edge2 (B->C) layer + output GEMM matter
// (h_B is dead code in the reference).
//
// R2: atomics-free aggregation via CSR counting sort.
//   memset : zero cnt|fillc (2N ints)
//   K_hist : cnt[d]++                                 (int atomics, 800k)
//   K_scan1/2 : exclusive scan of cnt -> offs (+ block partials)
//   K_fill : srcs[offs[d]+fillc[d]++] = s             (int atomics, 800k)
//   K_gather: per-node wave: agg_norm[r] = sum_j w*xB[s_j] / max(sum w,1e-6)
//   K2     : y = agg@Wl + x_C@Wcomb + bc; relu; LN; cnt-select -> hC (in-place)
//   K3     : d_out = hC @ Wout + bout
//
// ws layout (4B units): [cnt N | fillc N | offs N | part 128 | srcs E | buf N*128]

#define HD 128
#define OD 64
#define SCAN_E 1024   // elements per scan block (256 thr x 4)

__device__ __forceinline__ float softplus_f(float x) {
    return fmaxf(x, 0.0f) + log1pf(expf(-fabsf(x)));
}
__device__ __forceinline__ float sigmoid_f(float x) {
    return 1.0f / (1.0f + expf(-x));
}

// ---------------------------------------------------------------- histogram
__global__ __launch_bounds__(256) void k_hist(
    const int* __restrict__ edge, int* __restrict__ cnt, int E)
{
    int e = blockIdx.x * 256 + threadIdx.x;
    if (e < E) atomicAdd(cnt + edge[E + e], 1);
}

// ---------------------------------------------------------------- scan (2-level)
__global__ __launch_bounds__(256) void k_scan1(
    const int* __restrict__ cnt, int* __restrict__ offs,
    int* __restrict__ part, int N)
{
    __shared__ int sh[256];
    const int t = threadIdx.x;
    const int base = blockIdx.x * SCAN_E + t * 4;
    int v[4], sum = 0;
#pragma unroll
    for (int i = 0; i < 4; ++i) {
        int idx = base + i;
        v[i] = (idx < N) ? cnt[idx] : 0;
        sum += v[i];
    }
    sh[t] = sum;
    __syncthreads();
    for (int off = 1; off < 256; off <<= 1) {
        int x = (t >= off) ? sh[t - off] : 0;
        __syncthreads();
        sh[t] += x;
        __syncthreads();
    }
    int run = (t > 0) ? sh[t - 1] : 0;
    if (t == 255) part[blockIdx.x] = sh[t];
#pragma unroll
    for (int i = 0; i < 4; ++i) {
        int idx = base + i;
        if (idx < N) offs[idx] = run;
        run += v[i];
    }
}

__global__ __launch_bounds__(128) void k_scan2(int* __restrict__ part, int NB)
{
    __shared__ int sh[128];
    const int t = threadIdx.x;
    sh[t] = (t < NB) ? part[t] : 0;
    __syncthreads();
    for (int off = 1; off < 128; off <<= 1) {
        int x = (t >= off) ? sh[t - off] : 0;
        __syncthreads();
        sh[t] += x;
        __syncthreads();
    }
    if (t < NB) part[t] = (t > 0) ? sh[t - 1] : 0;
}

// ---------------------------------------------------------------- CSR fill
__global__ __launch_bounds__(256) void k_fill(
    const int* __restrict__ edge, const int* __restrict__ offs,
    const int* __restrict__ part, int* __restrict__ fillc,
    int* __restrict__ srcs, int E)
{
    int e = blockIdx.x * 256 + threadIdx.x;
    if (e >= E) return;
    int s = edge[e];
    int d = edge[E + e];
    int pos = offs[d] + part[d >> 10] + atomicAdd(fillc + d, 1);
    srcs[pos] = s;
}

// ---------------------------------------------------------------- gather
// one 64-lane wave per destination node; lane owns 2 columns (float2)
__global__ __launch_bounds__(256) void k_gather(
    const float* __restrict__ xB, const float* __restrict__ tB,
    const float* __restrict__ tC, const int* __restrict__ srcs,
    const int* __restrict__ offs, const int* __restrict__ part,
    const int* __restrict__ cnt, const float* __restrict__ lam_raw,
    float* __restrict__ aggn, int N)
{
    const int wave = (blockIdx.x * 256 + threadIdx.x) >> 6;
    const int lane = threadIdx.x & 63;
    if (wave >= N) return;
    const int r = wave;
    const int degc = cnt[r];

    float2* dst = reinterpret_cast<float2*>(aggn + (size_t)r * HD) + lane;
    if (degc == 0) {               // never selected; keep defined (no stale NaN)
        *dst = make_float2(0.f, 0.f);
        return;
    }

    const int start = offs[r] + part[r >> 10];
    const float lam = softplus_f(lam_raw[0]) + 1e-8f;
    const float tc  = tC[r];

    float ax = 0.f, ay = 0.f, sumw = 0.f;
    for (int j = 0; j < degc; ++j) {
        int s = srcs[start + j];
        float dt = fmaxf(tc - tB[s], 0.0f);
        float w  = expf(fmaxf(-lam * dt, -60.0f));
        float2 x = *(reinterpret_cast<const float2*>(xB + (size_t)s * HD) + lane);
        ax = fmaf(w, x.x, ax);
        ay = fmaf(w, x.y, ay);
        sumw += w;
    }
    float inv = 1.0f / fmaxf(sumw, 1e-6f);
    *dst = make_float2(ax * inv, ay * inv);
}

// ---------------------------------------------------------------- K2: layer
// block = 256 thr, tile = 32 rows x 128 cols, K=256 (A1=agg_norm, A2=x_C)
// 4 phases: (Wl,A1,kh0) (Wl,A1,kh1) (Wc,A2,kh0) (Wc,A2,kh1); acc persists.
// buf is read (agg rows of this block) then overwritten (hC rows) — in-place.
__global__ __launch_bounds__(256) void k_layer(
    const float* __restrict__ xC, float* buf,
    const int* __restrict__ cnt,
    const float* __restrict__ Wl, const float* __restrict__ W0,
    const float* __restrict__ W1, const float* __restrict__ bl,
    const float* __restrict__ b0, const float* __restrict__ b1,
    const float* __restrict__ gatep, const float* __restrict__ lng,
    const float* __restrict__ lnb, int N)
{
    __shared__ float Bs[64][128];   // 32 KB: weight K-half
    __shared__ float As[64][36];    // 9 KB : A-tile transposed [k][row], padded

    const int t     = threadIdx.x;
    const int cg    = t & 31;       // col group: cols cg*4..+3
    const int rg    = t >> 5;       // row group: rows rg*4..+3 (0..7)
    const int rbase = blockIdx.x * 32;
    const float g   = sigmoid_f(gatep[0]);

    float acc[4][4] = {};

    for (int ph = 0; ph < 4; ++ph) {
        const int mat = ph >> 1;    // 0: Wl vs agg, 1: Wcomb vs x_C
        const int kh  = ph & 1;     // K half

        // ---- stage B half (64x128), flat coalesced float4
        {
            const float* src0 = (mat == 0) ? Wl : W0;
#pragma unroll
            for (int i = 0; i < 8; ++i) {
                int f = t * 4 + i * 1024;
                float4 v = *reinterpret_cast<const float4*>(src0 + kh * 8192 + f);
                if (mat == 1) {
                    float4 v1 = *reinterpret_cast<const float4*>(W1 + kh * 8192 + f);
                    v.x = (1.f - g) * v.x + g * v1.x;
                    v.y = (1.f - g) * v.y + g * v1.y;
                    v.z = (1.f - g) * v.z + g * v1.z;
                    v.w = (1.f - g) * v.w + g * v1.w;
                }
                *reinterpret_cast<float4*>(&Bs[0][0] + f) = v;
            }
        }
        // ---- stage A half transposed: As[k][row]
        {
            const int rl = t & 31;
            const int k0 = (t >> 5) * 8;
            const int r  = rbase + rl;
            float av[8];
            if (r < N) {
                const float* src = (mat == 0) ? buf : xC;
                float4 u0 = *reinterpret_cast<const float4*>(src + (size_t)r * HD + kh * 64 + k0);
                float4 u1 = *reinterpret_cast<const float4*>(src + (size_t)r * HD + kh * 64 + k0 + 4);
                av[0] = u0.x; av[1] = u0.y; av[2] = u0.z; av[3] = u0.w;
                av[4] = u1.x; av[5] = u1.y; av[6] = u1.z; av[7] = u1.w;
            } else {
#pragma unroll
                for (int j = 0; j < 8; ++j) av[j] = 0.0f;
            }
#pragma unroll
            for (int j = 0; j < 8; ++j) As[k0 + j][rl] = av[j];   // conflict-free
        }
        __syncthreads();

#pragma unroll 4
        for (int k = 0; k < 64; ++k) {
            float4 a4 = *reinterpret_cast<const float4*>(&As[k][rg * 4]);
            float4 b4 = *reinterpret_cast<const float4*>(&Bs[k][cg * 4]);
            const float aa[4] = {a4.x, a4.y, a4.z, a4.w};
            const float bb[4] = {b4.x, b4.y, b4.z, b4.w};
#pragma unroll
            for (int i = 0; i < 4; ++i)
#pragma unroll
                for (int j = 0; j < 4; ++j)
                    acc[i][j] = fmaf(aa[i], bb[j], acc[i][j]);
        }
        __syncthreads();
    }

    // ---- epilogue: bias, relu, LN (row reduce over the 32-thread col group)
    float4 blv = *reinterpret_cast<const float4*>(bl + cg * 4);
    float4 b0v = *reinterpret_cast<const float4*>(b0 + cg * 4);
    float4 b1v = *reinterpret_cast<const float4*>(b1 + cg * 4);
    const float bc[4] = {
        blv.x + (1.f - g) * b0v.x + g * b1v.x,
        blv.y + (1.f - g) * b0v.y + g * b1v.y,
        blv.z + (1.f - g) * b0v.z + g * b1v.z,
        blv.w + (1.f - g) * b0v.w + g * b1v.w};
    float4 lngv = *reinterpret_cast<const float4*>(lng + cg * 4);
    float4 lnbv = *reinterpret_cast<const float4*>(lnb + cg * 4);
    const float ga[4] = {lngv.x, lngv.y, lngv.z, lngv.w};
    const float be[4] = {lnbv.x, lnbv.y, lnbv.z, lnbv.w};

#pragma unroll
    for (int i = 0; i < 4; ++i) {
        float y[4], s = 0.f, q = 0.f;
#pragma unroll
        for (int j = 0; j < 4; ++j) {
            float v = fmaxf(acc[i][j] + bc[j], 0.0f);
            y[j] = v; s += v; q += v * v;
        }
#pragma unroll
        for (int m = 1; m < 32; m <<= 1) {
            s += __shfl_xor(s, m);
            q += __shfl_xor(q, m);
        }
        float mu   = s * (1.0f / 128.0f);
        float var  = q * (1.0f / 128.0f) - mu * mu;
        float rstd = rsqrtf(var + 1e-5f);

        int r = rbase + rg * 4 + i;
        if (r < N) {
            float4 res;
            if (cnt[r] > 0) {
                res.x = (y[0] - mu) * rstd * ga[0] + be[0];
                res.y = (y[1] - mu) * rstd * ga[1] + be[1];
                res.z = (y[2] - mu) * rstd * ga[2] + be[2];
                res.w = (y[3] - mu) * rstd * ga[3] + be[3];
            } else {
                res = *reinterpret_cast<const float4*>(xC + (size_t)r * HD + cg * 4);
            }
            *reinterpret_cast<float4*>(buf + (size_t)r * HD + cg * 4) = res;
        }
    }
}

// ---------------------------------------------------------------- K3: out GEMM
// block = 256 thr, tile = 32 rows x 64 cols, K=128
__global__ __launch_bounds__(256) void k_out(
    const float* __restrict__ hC, const float* __restrict__ Wout,
    const float* __restrict__ bout, float* __restrict__ out, int N)
{
    __shared__ float Bs[128][64];   // 32 KB Wout
    __shared__ float As[128][36];   // 18 KB A-tile transposed, padded

    const int t     = threadIdx.x;
    const int rbase = blockIdx.x * 32;

#pragma unroll
    for (int i = 0; i < 8; ++i) {
        int f = t * 4 + i * 1024;
        *reinterpret_cast<float4*>(&Bs[0][0] + f) =
            *reinterpret_cast<const float4*>(Wout + f);
    }
    {
        const int rl = t & 31;
        const int k0 = (t >> 5) * 16;
        const int r  = rbase + rl;
        float av[16];
        if (r < N) {
#pragma unroll
            for (int c = 0; c < 4; ++c) {
                float4 u = *reinterpret_cast<const float4*>(hC + (size_t)r * HD + k0 + c * 4);
                av[c * 4 + 0] = u.x; av[c * 4 + 1] = u.y;
                av[c * 4 + 2] = u.z; av[c * 4 + 3] = u.w;
            }
        } else {
#pragma unroll
            for (int j = 0; j < 16; ++j) av[j] = 0.0f;
        }
#pragma unroll
        for (int j = 0; j < 16; ++j) As[k0 + j][rl] = av[j];   // conflict-free
    }
    __syncthreads();

    const int cg = t & 15;   // cols cg*4..+3
    const int rg = t >> 4;   // rows rg*2..+1 (0..15)
    float acc[2][4] = {};

#pragma unroll 4
    for (int k = 0; k < 128; ++k) {
        float2 a2 = *reinterpret_cast<const float2*>(&As[k][rg * 2]);
        float4 b4 = *reinterpret_cast<const float4*>(&Bs[k][cg * 4]);
        acc[0][0] = fmaf(a2.x, b4.x, acc[0][0]);
        acc[0][1] = fmaf(a2.x, b4.y, acc[0][1]);
        acc[0][2] = fmaf(a2.x, b4.z, acc[0][2]);
        acc[0][3] = fmaf(a2.x, b4.w, acc[0][3]);
        acc[1][0] = fmaf(a2.y, b4.x, acc[1][0]);
        acc[1][1] = fmaf(a2.y, b4.y, acc[1][1]);
        acc[1][2] = fmaf(a2.y, b4.z, acc[1][2]);
        acc[1][3] = fmaf(a2.y, b4.w, acc[1][3]);
    }

    float4 bo = *reinterpret_cast<const float4*>(bout + cg * 4);
#pragma unroll
    for (int i = 0; i < 2; ++i) {
        int r = rbase + rg * 2 + i;
        if (r < N) {
            float4 res;
            res.x = acc[i][0] + bo.x;
            res.y = acc[i][1] + bo.y;
            res.z = acc[i][2] + bo.z;
            res.w = acc[i][3] + bo.w;
            *reinterpret_cast<float4*>(out + (size_t)r * OD + cg * 4) = res;
        }
    }
}

// ---------------------------------------------------------------- launch
extern "C" void kernel_launch(void* const* d_in, const int* in_sizes, int n_in,
                              void* d_out, int out_size, void* d_ws, size_t ws_size,
                              hipStream_t stream) {
    const float* xB    = (const float*)d_in[1];
    const float* xC    = (const float*)d_in[2];
    const float* tB    = (const float*)d_in[4];
    const float* tC    = (const float*)d_in[5];
    const int*   edge2 = (const int*)d_in[7];
    const float* Wl1   = (const float*)d_in[18];
    const float* bl1   = (const float*)d_in[19];
    const float* W01   = (const float*)d_in[20];
    const float* b01   = (const float*)d_in[21];
    const float* W11   = (const float*)d_in[22];
    const float* b11   = (const float*)d_in[23];
    const float* gate1 = (const float*)d_in[24];
    const float* lam1  = (const float*)d_in[25];
    const float* lng1  = (const float*)d_in[26];
    const float* lnb1  = (const float*)d_in[27];
    const float* Wout  = (const float*)d_in[28];
    const float* bout  = (const float*)d_in[29];

    const int N = in_sizes[2] / HD;
    const int E = in_sizes[7] / 2;

    int*   cnt   = (int*)d_ws;
    int*   fillc = cnt + N;
    int*   offs  = fillc + N;
    int*   part  = offs + N;
    int*   srcs  = part + 128;
    float* buf   = (float*)(srcs + E);   // agg_norm, then hC in-place

    hipMemsetAsync(cnt, 0, (size_t)2 * N * sizeof(int), stream);

    dim3 blk(256);
    const int gE = (E + 255) / 256;
    const int NB = (N + SCAN_E - 1) / SCAN_E;

    k_hist <<<gE, blk, 0, stream>>>(edge2, cnt, E);
    k_scan1<<<NB, blk, 0, stream>>>(cnt, offs, part, N);
    k_scan2<<<1, 128, 0, stream>>>(part, NB);
    k_fill <<<gE, blk, 0, stream>>>(edge2, offs, part, fillc, srcs, E);

    const int gN64 = (N * 64 + 255) / 256;
    k_gather<<<gN64, blk, 0, stream>>>(xB, tB, tC, srcs, offs, part, cnt,
                                       lam1, buf, N);

    const int gT = (N + 31) / 32;
    k_layer<<<gT, blk, 0, stream>>>(xC, buf, cnt, Wl1, W01, W11,
                                    bl1, b01, b11, gate1, lng1, lnb1, N);
    k_out  <<<gT, blk, 0, stream>>>(buf, Wout, bout, (float*)d_out, N);
}

// Round 7
// 282.702 us; speedup vs baseline: 5.5362x; 1.1585x over previous
//
#include <hip/hip_runtime.h>

// MetaPathGNN — only the edge2 (B->C) layer + output GEMM matter
// (h_B is dead code in the reference).
//
// R3 (fourth submit; source unchanged — four consecutive UnresponsiveContainer
// infra failures on pod dual-thick-firm-lion; this source has never executed):
// precomputed edge weights, ILP-2 gather, 64-row GEMM tiles.
//   memset : zero cnt|fillc (2N ints)
//   K_hist : cnt[d]++
//   K_scan1/2 : exclusive scan of cnt -> offs (+ block partials)
//   K_fillw: srcw[offs[d]+fillc[d]++] = (s, w)   (w = exp(-lam*dt) precomputed)
//   K_wprep: Wc = (1-g)W0 + g*W1 ; bc = bl + (1-g)b0 + g*b1
//   K_gather: per-node wave, 2 edges in flight: aggn[r] = sum w*xB[s] / sum w
//   K2     : y = agg@Wl + x_C@Wc + bc; relu; LN; cnt-select -> hC (in-place)
//   K3     : d_out = hC @ Wout + bout
//
// ws (4B units): [cnt N | fillc N | offs N | part 128 | srcw 2E | Wc 16384 | bc 128 | buf N*128]

#define HD 128
#define OD 64
#define SCAN_E 1024   // elements per scan block (256 thr x 4)

__device__ __forceinline__ float softplus_f(float x) {
    return fmaxf(x, 0.0f) + log1pf(expf(-fabsf(x)));
}
__device__ __forceinline__ float sigmoid_f(float x) {
    return 1.0f / (1.0f + expf(-x));
}

// ---------------------------------------------------------------- histogram
__global__ __launch_bounds__(256) void k_hist(
    const int* __restrict__ edge, int* __restrict__ cnt, int E)
{
    int e = blockIdx.x * 256 + threadIdx.x;
    if (e < E) atomicAdd(cnt + edge[E + e], 1);
}

// ---------------------------------------------------------------- scan (2-level)
__global__ __launch_bounds__(256) void k_scan1(
    const int* __restrict__ cnt, int* __restrict__ offs,
    int* __restrict__ part, int N)
{
    __shared__ int sh[256];
    const int t = threadIdx.x;
    const int base = blockIdx.x * SCAN_E + t * 4;
    int v[4], sum = 0;
#pragma unroll
    for (int i = 0; i < 4; ++i) {
        int idx = base + i;
        v[i] = (idx < N) ? cnt[idx] : 0;
        sum += v[i];
    }
    sh[t] = sum;
    __syncthreads();
    for (int off = 1; off < 256; off <<= 1) {
        int x = (t >= off) ? sh[t - off] : 0;
        __syncthreads();
        sh[t] += x;
        __syncthreads();
    }
    int run = (t > 0) ? sh[t - 1] : 0;
    if (t == 255) part[blockIdx.x] = sh[t];
#pragma unroll
    for (int i = 0; i < 4; ++i) {
        int idx = base + i;
        if (idx < N) offs[idx] = run;
        run += v[i];
    }
}

__global__ __launch_bounds__(128) void k_scan2(int* __restrict__ part, int NB)
{
    __shared__ int sh[128];
    const int t = threadIdx.x;
    sh[t] = (t < NB) ? part[t] : 0;
    __syncthreads();
    for (int off = 1; off < 128; off <<= 1) {
        int x = (t >= off) ? sh[t - off] : 0;
        __syncthreads();
        sh[t] += x;
        __syncthreads();
    }
    if (t < NB) part[t] = (t > 0) ? sh[t - 1] : 0;
}

// ---------------------------------------------------------------- CSR fill + weight
__global__ __launch_bounds__(256) void k_fillw(
    const int* __restrict__ edge, const float* __restrict__ tB,
    const float* __restrict__ tC, const float* __restrict__ lam_raw,
    const int* __restrict__ offs, const int* __restrict__ part,
    int* __restrict__ fillc, int2* __restrict__ srcw, int E)
{
    int e = blockIdx.x * 256 + threadIdx.x;
    if (e >= E) return;
    int s = edge[e];
    int d = edge[E + e];
    float lam = softplus_f(lam_raw[0]) + 1e-8f;
    float dt  = fmaxf(tC[d] - tB[s], 0.0f);
    float w   = expf(fmaxf(-lam * dt, -60.0f));
    int pos = offs[d] + part[d >> 10] + atomicAdd(fillc + d, 1);
    srcw[pos] = make_int2(s, __float_as_int(w));
}

// ---------------------------------------------------------------- weight prep
__global__ __launch_bounds__(256) void k_wprep(
    const float* __restrict__ W0, const float* __restrict__ W1,
    const float* __restrict__ bl, const float* __restrict__ b0,
    const float* __restrict__ b1, const float* __restrict__ gatep,
    float* __restrict__ Wc, float* __restrict__ bc)
{
    const float g = sigmoid_f(gatep[0]);
    int i = blockIdx.x * 256 + threadIdx.x;   // 4096 float4s
    float4 a = reinterpret_cast<const float4*>(W0)[i];
    float4 b = reinterpret_cast<const float4*>(W1)[i];
    float4 r;
    r.x = (1.f - g) * a.x + g * b.x;
    r.y = (1.f - g) * a.y + g * b.y;
    r.z = (1.f - g) * a.z + g * b.z;
    r.w = (1.f - g) * a.w + g * b.w;
    reinterpret_cast<float4*>(Wc)[i] = r;
    if (blockIdx.x == 0 && threadIdx.x < HD) {
        int t = threadIdx.x;
        bc[t] = bl[t] + (1.f - g) * b0[t] + g * b1[t];
    }
}

// ---------------------------------------------------------------- gather
// one 64-lane wave per destination node; 2 edges in flight (32 lanes x float4)
__global__ __launch_bounds__(256) void k_gather(
    const float* __restrict__ xB, const int2* __restrict__ srcw,
    const int* __restrict__ offs, const int* __restrict__ part,
    const int* __restrict__ cnt, float* __restrict__ aggn, int N)
{
    const int wave = (blockIdx.x * 256 + threadIdx.x) >> 6;
    const int lane = threadIdx.x & 63;
    const int half = lane >> 5;
    const int l5   = lane & 31;
    if (wave >= N) return;
    const int r    = wave;
    const int degc = cnt[r];

    float4* dst = reinterpret_cast<float4*>(aggn + (size_t)r * HD) + l5;
    if (degc == 0) {               // never selected; keep defined
        if (half == 0) *dst = make_float4(0.f, 0.f, 0.f, 0.f);
        return;
    }

    const int start = offs[r] + part[r >> 10];
    float4 acc = make_float4(0.f, 0.f, 0.f, 0.f);
    float sumw = 0.f;
#pragma unroll 2
    for (int j = half; j < degc; j += 2) {
        int2 sw = srcw[start + j];
        float w = __int_as_float(sw.y);
        const float4 x = *(reinterpret_cast<const float4*>(
                               xB + (size_t)sw.x * HD) + l5);
        acc.x = fmaf(w, x.x, acc.x);
        acc.y = fmaf(w, x.y, acc.y);
        acc.z = fmaf(w, x.z, acc.z);
        acc.w = fmaf(w, x.w, acc.w);
        sumw += w;
    }
    // combine the two halves
    acc.x += __shfl_xor(acc.x, 32);
    acc.y += __shfl_xor(acc.y, 32);
    acc.z += __shfl_xor(acc.z, 32);
    acc.w += __shfl_xor(acc.w, 32);
    sumw  += __shfl_xor(sumw, 32);
    float inv = 1.0f / fmaxf(sumw, 1e-6f);
    if (half == 0) {
        acc.x *= inv; acc.y *= inv; acc.z *= inv; acc.w *= inv;
        *dst = acc;
    }
}

// ---------------------------------------------------------------- K2: layer
// block = 256 thr, tile = 64 rows x 128 cols, K=256 (A1=agg_norm, A2=x_C)
// 4 phases: (Wl,A1,kh0) (Wl,A1,kh1) (Wc,A2,kh0) (Wc,A2,kh1); acc persists.
// buf is read (agg rows of this block) then overwritten (hC rows) — in-place.
__global__ __launch_bounds__(256) void k_layer(
    const float* __restrict__ xC, float* buf,
    const int* __restrict__ cnt,
    const float* __restrict__ Wl, const float* __restrict__ Wc,
    const float* __restrict__ bc, const float* __restrict__ lng,
    const float* __restrict__ lnb, int N)
{
    __shared__ float Bs[64][128];   // 32 KB: weight K-half
    __shared__ float As[64][68];    // 17 KB: A-tile transposed [k][row], padded

    const int t     = threadIdx.x;
    const int cg    = t & 31;       // col group: cols cg*4..+3
    const int rg    = t >> 5;       // row group: rows rg*8..+7 (0..7)
    const int rbase = blockIdx.x * 64;

    float acc[8][4] = {};

    for (int ph = 0; ph < 4; ++ph) {
        const int mat = ph >> 1;    // 0: Wl vs agg, 1: Wc vs x_C
        const int kh  = ph & 1;     // K half

        // ---- stage B half (64x128), flat coalesced float4
        {
            const float* B = (mat == 0) ? Wl : Wc;
#pragma unroll
            for (int i = 0; i < 8; ++i) {
                int f = t * 4 + i * 1024;
                *reinterpret_cast<float4*>(&Bs[0][0] + f) =
                    *reinterpret_cast<const float4*>(B + kh * 8192 + f);
            }
        }
        // ---- stage A half transposed: As[k][row]
        {
            const int rl = t & 63;
            const int kq = t >> 6;          // 0..3
            const int r  = rbase + rl;
            const float* src = (mat == 0) ? buf : xC;
            float av[16];
            if (r < N) {
#pragma unroll
                for (int c = 0; c < 4; ++c) {
                    float4 u = *reinterpret_cast<const float4*>(
                        src + (size_t)r * HD + kh * 64 + kq * 16 + c * 4);
                    av[c * 4 + 0] = u.x; av[c * 4 + 1] = u.y;
                    av[c * 4 + 2] = u.z; av[c * 4 + 3] = u.w;
                }
            } else {
#pragma unroll
                for (int j = 0; j < 16; ++j) av[j] = 0.0f;
            }
#pragma unroll
            for (int j = 0; j < 16; ++j) As[kq * 16 + j][rl] = av[j];
        }
        __syncthreads();

#pragma unroll 8
        for (int k = 0; k < 64; ++k) {
            float4 b4 = *reinterpret_cast<const float4*>(&Bs[k][cg * 4]);
            float4 a0 = *reinterpret_cast<const float4*>(&As[k][rg * 8]);
            float4 a1 = *reinterpret_cast<const float4*>(&As[k][rg * 8 + 4]);
            const float aa[8] = {a0.x, a0.y, a0.z, a0.w, a1.x, a1.y, a1.z, a1.w};
#pragma unroll
            for (int i = 0; i < 8; ++i) {
                acc[i][0] = fmaf(aa[i], b4.x, acc[i][0]);
                acc[i][1] = fmaf(aa[i], b4.y, acc[i][1]);
                acc[i][2] = fmaf(aa[i], b4.z, acc[i][2]);
                acc[i][3] = fmaf(aa[i], b4.w, acc[i][3]);
            }
        }
        __syncthreads();
    }

    // ---- epilogue: bias, relu, LN (row reduce over the 32-thread col group)
    float4 bcv  = *reinterpret_cast<const float4*>(bc + cg * 4);
    float4 lngv = *reinterpret_cast<const float4*>(lng + cg * 4);
    float4 lnbv = *reinterpret_cast<const float4*>(lnb + cg * 4);
    const float bb[4] = {bcv.x, bcv.y, bcv.z, bcv.w};
    const float ga[4] = {lngv.x, lngv.y, lngv.z, lngv.w};
    const float be[4] = {lnbv.x, lnbv.y, lnbv.z, lnbv.w};

#pragma unroll
    for (int i = 0; i < 8; ++i) {
        float y[4], s = 0.f, q = 0.f;
#pragma unroll
        for (int j = 0; j < 4; ++j) {
            float v = fmaxf(acc[i][j] + bb[j], 0.0f);
            y[j] = v; s += v; q += v * v;
        }
#pragma unroll
        for (int m = 1; m < 32; m <<= 1) {
            s += __shfl_xor(s, m);
            q += __shfl_xor(q, m);
        }
        float mu   = s * (1.0f / 128.0f);
        float var  = q * (1.0f / 128.0f) - mu * mu;
        float rstd = rsqrtf(var + 1e-5f);

        int r = rbase + rg * 8 + i;
        if (r < N) {
            float4 res;
            if (cnt[r] > 0) {
                res.x = (y[0] - mu) * rstd * ga[0] + be[0];
                res.y = (y[1] - mu) * rstd * ga[1] + be[1];
                res.z = (y[2] - mu) * rstd * ga[2] + be[2];
                res.w = (y[3] - mu) * rstd * ga[3] + be[3];
            } else {
                res = *reinterpret_cast<const float4*>(xC + (size_t)r * HD + cg * 4);
            }
            *reinterpret_cast<float4*>(buf + (size_t)r * HD + cg * 4) = res;
        }
    }
}

// ---------------------------------------------------------------- K3: out GEMM
// block = 256 thr, tile = 64 rows x 64 cols, K=128, acc 4x4
__global__ __launch_bounds__(256) void k_out(
    const float* __restrict__ hC, const float* __restrict__ Wout,
    const float* __restrict__ bout, float* __restrict__ out, int N)
{
    __shared__ float Bs[128][64];   // 32 KB Wout
    __shared__ float As[128][68];   // 35 KB A-tile transposed, padded

    const int t     = threadIdx.x;
    const int rbase = blockIdx.x * 64;

#pragma unroll
    for (int i = 0; i < 8; ++i) {
        int f = t * 4 + i * 1024;
        *reinterpret_cast<float4*>(&Bs[0][0] + f) =
            *reinterpret_cast<const float4*>(Wout + f);
    }
    {
        const int rl = t & 63;
        const int kq = t >> 6;          // 0..3
        const int r  = rbase + rl;
        float av[32];
        if (r < N) {
#pragma unroll
            for (int c = 0; c < 8; ++c) {
                float4 u = *reinterpret_cast<const float4*>(
                    hC + (size_t)r * HD + kq * 32 + c * 4);
                av[c * 4 + 0] = u.x; av[c * 4 + 1] = u.y;
                av[c * 4 + 2] = u.z; av[c * 4 + 3] = u.w;
            }
        } else {
#pragma unroll
            for (int j = 0; j < 32; ++j) av[j] = 0.0f;
        }
#pragma unroll
        for (int j = 0; j < 32; ++j) As[kq * 32 + j][rl] = av[j];
    }
    __syncthreads();

    const int cg = t & 15;   // cols cg*4..+3
    const int rg = t >> 4;   // rows rg*4..+3 (0..15)
    float acc[4][4] = {};

#pragma unroll 8
    for (int k = 0; k < 128; ++k) {
        float4 a4 = *reinterpret_cast<const float4*>(&As[k][rg * 4]);
        float4 b4 = *reinterpret_cast<const float4*>(&Bs[k][cg * 4]);
        const float aa[4] = {a4.x, a4.y, a4.z, a4.w};
#pragma unroll
        for (int i = 0; i < 4; ++i) {
            acc[i][0] = fmaf(aa[i], b4.x, acc[i][0]);
            acc[i][1] = fmaf(aa[i], b4.y, acc[i][1]);
            acc[i][2] = fmaf(aa[i], b4.z, acc[i][2]);
            acc[i][3] = fmaf(aa[i], b4.w, acc[i][3]);
        }
    }

    float4 bo = *reinterpret_cast<const float4*>(bout + cg * 4);
#pragma unroll
    for (int i = 0; i < 4; ++i) {
        int r = rbase + rg * 4 + i;
        if (r < N) {
            float4 res;
            res.x = acc[i][0] + bo.x;
            res.y = acc[i][1] + bo.y;
            res.z = acc[i][2] + bo.z;
            res.w = acc[i][3] + bo.w;
            *reinterpret_cast<float4*>(out + (size_t)r * OD + cg * 4) = res;
        }
    }
}

// ---------------------------------------------------------------- launch
extern "C" void kernel_launch(void* const* d_in, const int* in_sizes, int n_in,
                              void* d_out, int out_size, void* d_ws, size_t ws_size,
                              hipStream_t stream) {
    const float* xB    = (const float*)d_in[1];
    const float* xC    = (const float*)d_in[2];
    const float* tB    = (const float*)d_in[4];
    const float* tC    = (const float*)d_in[5];
    const int*   edge2 = (const int*)d_in[7];
    const float* Wl1   = (const float*)d_in[18];
    const float* bl1   = (const float*)d_in[19];
    const float* W01   = (const float*)d_in[20];
    const float* b01   = (const float*)d_in[21];
    const float* W11   = (const float*)d_in[22];
    const float* b11   = (const float*)d_in[23];
    const float* gate1 = (const float*)d_in[24];
    const float* lam1  = (const float*)d_in[25];
    const float* lng1  = (const float*)d_in[26];
    const float* lnb1  = (const float*)d_in[27];
    const float* Wout  = (const float*)d_in[28];
    const float* bout  = (const float*)d_in[29];

    const int N = in_sizes[2] / HD;
    const int E = in_sizes[7] / 2;

    int*   cnt   = (int*)d_ws;
    int*   fillc = cnt + N;
    int*   offs  = fillc + N;
    int*   part  = offs + N;
    int2*  srcw  = (int2*)(part + 128);
    float* Wc    = (float*)(srcw + E);
    float* bc    = Wc + HD * HD;
    float* buf   = bc + HD;              // agg_norm, then hC in-place

    hipMemsetAsync(cnt, 0, (size_t)2 * N * sizeof(int), stream);

    dim3 blk(256);
    const int gE = (E + 255) / 256;
    const int NB = (N + SCAN_E - 1) / SCAN_E;

    k_wprep<<<HD * HD / 1024, blk, 0, stream>>>(W01, W11, bl1, b01, b11, gate1, Wc, bc);
    k_hist <<<gE, blk, 0, stream>>>(edge2, cnt, E);
    k_scan1<<<NB, blk, 0, stream>>>(cnt, offs, part, N);
    k_scan2<<<1, 128, 0, stream>>>(part, NB);
    k_fillw<<<gE, blk, 0, stream>>>(edge2, tB, tC, lam1, offs, part, fillc, srcw, E);

    const int gN64 = (N * 64 + 255) / 256;
    k_gather<<<gN64, blk, 0, stream>>>(xB, srcw, offs, part, cnt, buf, N);

    const int gT = (N + 63) / 64;
    k_layer<<<gT, blk, 0, stream>>>(xC, buf, cnt, Wl1, Wc, bc, lng1, lnb1, N);
    k_out  <<<gT, blk, 0, stream>>>(buf, Wout, bout, (float*)d_out, N);
}

// Round 9
// 237.045 us; speedup vs baseline: 6.6026x; 1.1926x over previous
//
#include <hip/hip_runtime.h>

// MetaPathGNN — only the edge2 (B->C) layer + output GEMM matter
// (h_B is dead code in the reference).
//
// R8 (resubmit; source unchanged — UnresponsiveContainer infra failure,
// never executed): K2/K3 as zero-LDS split-bf16 MFMA GEMMs (R3's fp32
// k_layer was LDS-bandwidth-bound at 124 µs, occupancy 17.9%).
//   memset : zero cnt|fillc (2N ints)
//   K_hist : cnt[d]++
//   K_scan1/2 : exclusive scan of cnt -> offs (+ block partials)
//   K_fillw: srcw[offs[d]+fillc[d]++] = (s, w)
//   K_wprep: split Wl, Wc=(1-g)W0+gW1, Wout into transposed packed bf16
//            hi/lo planes [kc][n][ks=32]; bc = bl+(1-g)b0+g*b1
//   K_gather: per-node wave, 2 edges in flight: aggn[r] = sum w*xB[s]/sum w
//   K2_mfma: y = agg@Wl + xC@Wc + bc; relu; LN; cnt-select -> hC (in buf)
//            A-rows read global->reg, split bf16 hi/lo; B-frags read from
//            L2-resident packed planes; 3-term MFMA; LN via shfl in-register.
//   K3_mfma: d_out = hC @ Wout + bout  (same structure)
//
// ws (4B units): [cnt N | fillc N | offs N | part 128 | srcw 2E |
//                 planes: wlh/wll/wch/wcl 16384ush each, woh/wol 8192ush |
//                 bc 128 | buf N*128]

#define HD 128
#define OD 64
#define SCAN_E 1024

typedef unsigned short u16;
typedef short v8s __attribute__((ext_vector_type(8)));
typedef float v4f __attribute__((ext_vector_type(4)));

union Frag {
    unsigned int u[4];
    uint4 q;
    v8s v;
};

__device__ __forceinline__ float softplus_f(float x) {
    return fmaxf(x, 0.0f) + log1pf(expf(-fabsf(x)));
}
__device__ __forceinline__ float sigmoid_f(float x) {
    return 1.0f / (1.0f + expf(-x));
}

// split x into bf16 hi + bf16 lo (truncation split; residual ~2^-17 |x|)
__device__ __forceinline__ void split_store(float x, u16* ph, u16* pl) {
    unsigned int b = __float_as_uint(x);
    unsigned int h = b & 0xffff0000u;
    *ph = (u16)(h >> 16);
    float r = x - __uint_as_float(h);
    *pl = (u16)(__float_as_uint(r) >> 16);
}

// 8 floats -> 4 packed dwords hi, 4 packed dwords lo (2 bf16 per dword)
__device__ __forceinline__ void cvt_split8(const float* f, unsigned int* hi,
                                           unsigned int* lo) {
#pragma unroll
    for (int j = 0; j < 4; ++j) {
        unsigned int b0 = __float_as_uint(f[2 * j]);
        unsigned int b1 = __float_as_uint(f[2 * j + 1]);
        unsigned int h0 = b0 & 0xffff0000u;
        unsigned int h1 = b1 & 0xffff0000u;
        hi[j] = (h0 >> 16) | h1;
        float r0 = f[2 * j]     - __uint_as_float(h0);
        float r1 = f[2 * j + 1] - __uint_as_float(h1);
        lo[j] = (__float_as_uint(r0) >> 16) | (__float_as_uint(r1) & 0xffff0000u);
    }
}

// ---------------------------------------------------------------- histogram
__global__ __launch_bounds__(256) void k_hist(
    const int* __restrict__ edge, int* __restrict__ cnt, int E)
{
    int e = blockIdx.x * 256 + threadIdx.x;
    if (e < E) atomicAdd(cnt + edge[E + e], 1);
}

// ---------------------------------------------------------------- scan (2-level)
__global__ __launch_bounds__(256) void k_scan1(
    const int* __restrict__ cnt, int* __restrict__ offs,
    int* __restrict__ part, int N)
{
    __shared__ int sh[256];
    const int t = threadIdx.x;
    const int base = blockIdx.x * SCAN_E + t * 4;
    int v[4], sum = 0;
#pragma unroll
    for (int i = 0; i < 4; ++i) {
        int idx = base + i;
        v[i] = (idx < N) ? cnt[idx] : 0;
        sum += v[i];
    }
    sh[t] = sum;
    __syncthreads();
    for (int off = 1; off < 256; off <<= 1) {
        int x = (t >= off) ? sh[t - off] : 0;
        __syncthreads();
        sh[t] += x;
        __syncthreads();
    }
    int run = (t > 0) ? sh[t - 1] : 0;
    if (t == 255) part[blockIdx.x] = sh[t];
#pragma unroll
    for (int i = 0; i < 4; ++i) {
        int idx = base + i;
        if (idx < N) offs[idx] = run;
        run += v[i];
    }
}

__global__ __launch_bounds__(128) void k_scan2(int* __restrict__ part, int NB)
{
    __shared__ int sh[128];
    const int t = threadIdx.x;
    sh[t] = (t < NB) ? part[t] : 0;
    __syncthreads();
    for (int off = 1; off < 128; off <<= 1) {
        int x = (t >= off) ? sh[t - off] : 0;
        __syncthreads();
        sh[t] += x;
        __syncthreads();
    }
    if (t < NB) part[t] = (t > 0) ? sh[t - 1] : 0;
}

// ---------------------------------------------------------------- CSR fill + weight
__global__ __launch_bounds__(256) void k_fillw(
    const int* __restrict__ edge, const float* __restrict__ tB,
    const float* __restrict__ tC, const float* __restrict__ lam_raw,
    const int* __restrict__ offs, const int* __restrict__ part,
    int* __restrict__ fillc, int2* __restrict__ srcw, int E)
{
    int e = blockIdx.x * 256 + threadIdx.x;
    if (e >= E) return;
    int s = edge[e];
    int d = edge[E + e];
    float lam = softplus_f(lam_raw[0]) + 1e-8f;
    float dt  = fmaxf(tC[d] - tB[s], 0.0f);
    float w   = expf(fmaxf(-lam * dt, -60.0f));
    int pos = offs[d] + part[d >> 10] + atomicAdd(fillc + d, 1);
    srcw[pos] = make_int2(s, __float_as_int(w));
}

// ---------------------------------------------------------------- weight prep
// Wl, Wc=(1-g)W0+gW1 (128x128), Wout (128x64) -> transposed packed planes:
// [kc=k>>5][n][ks=k&31] bf16 hi/lo ushorts.  Also bc.
__global__ __launch_bounds__(256) void k_wprep(
    const float* __restrict__ Wl, const float* __restrict__ W0,
    const float* __restrict__ W1, const float* __restrict__ Wout,
    const float* __restrict__ bl, const float* __restrict__ b0,
    const float* __restrict__ b1, const float* __restrict__ gatep,
    u16* __restrict__ wlh, u16* __restrict__ wll,
    u16* __restrict__ wch, u16* __restrict__ wcl,
    u16* __restrict__ woh, u16* __restrict__ wol, float* __restrict__ bc)
{
    int i = blockIdx.x * 256 + threadIdx.x;
    const float g = sigmoid_f(gatep[0]);
    if (i < 16384) {
        int n = i >> 7, k = i & 127;
        float a  = Wl[k * 128 + n];
        float w0 = W0[k * 128 + n];
        float w1 = W1[k * 128 + n];
        float c  = (1.f - g) * w0 + g * w1;
        int off = ((k >> 5) * 128 + n) * 32 + (k & 31);
        split_store(a, wlh + off, wll + off);
        split_store(c, wch + off, wcl + off);
    } else if (i < 24576) {
        int j = i - 16384;
        int n = j >> 7, k = j & 127;          // n 0..63, k 0..127
        float v = Wout[k * 64 + n];
        int off = ((k >> 5) * 64 + n) * 32 + (k & 31);
        split_store(v, woh + off, wol + off);
    } else if (i < 24704) {
        int t = i - 24576;
        bc[t] = bl[t] + (1.f - g) * b0[t] + g * b1[t];
    }
}

// ---------------------------------------------------------------- gather
__global__ __launch_bounds__(256) void k_gather(
    const float* __restrict__ xB, const int2* __restrict__ srcw,
    const int* __restrict__ offs, const int* __restrict__ part,
    const int* __restrict__ cnt, float* __restrict__ aggn, int N)
{
    const int wave = (blockIdx.x * 256 + threadIdx.x) >> 6;
    const int lane = threadIdx.x & 63;
    const int half = lane >> 5;
    const int l5   = lane & 31;
    if (wave >= N) return;
    const int r    = wave;
    const int degc = cnt[r];

    float4* dst = reinterpret_cast<float4*>(aggn + (size_t)r * HD) + l5;
    if (degc == 0) {
        if (half == 0) *dst = make_float4(0.f, 0.f, 0.f, 0.f);
        return;
    }

    const int start = offs[r] + part[r >> 10];
    float4 acc = make_float4(0.f, 0.f, 0.f, 0.f);
    float sumw = 0.f;
#pragma unroll 2
    for (int j = half; j < degc; j += 2) {
        int2 sw = srcw[start + j];
        float w = __int_as_float(sw.y);
        const float4 x = *(reinterpret_cast<const float4*>(
                               xB + (size_t)sw.x * HD) + l5);
        acc.x = fmaf(w, x.x, acc.x);
        acc.y = fmaf(w, x.y, acc.y);
        acc.z = fmaf(w, x.z, acc.z);
        acc.w = fmaf(w, x.w, acc.w);
        sumw += w;
    }
    acc.x += __shfl_xor(acc.x, 32);
    acc.y += __shfl_xor(acc.y, 32);
    acc.z += __shfl_xor(acc.z, 32);
    acc.w += __shfl_xor(acc.w, 32);
    sumw  += __shfl_xor(sumw, 32);
    float inv = 1.0f / fmaxf(sumw, 1e-6f);
    if (half == 0) {
        acc.x *= inv; acc.y *= inv; acc.z *= inv; acc.w *= inv;
        *dst = acc;
    }
}

// ---------------------------------------------------------------- K2: MFMA layer
// block = 256 thr = 4 waves; wave owns 32 rows x 128 cols (2 row-tiles x 8
// col-tiles of 16x16).  K=256 (agg@Wl then xC@Wc), chunks of 32.
// A: global->reg split-bf16.  B: packed planes via L2.  No LDS, no barriers.
__global__ __launch_bounds__(256) void k_layer_mfma(
    const float* __restrict__ xC, float* __restrict__ buf,
    const int* __restrict__ cnt,
    const u16* __restrict__ wlh, const u16* __restrict__ wll,
    const u16* __restrict__ wch, const u16* __restrict__ wcl,
    const float* __restrict__ bc, const float* __restrict__ lng,
    const float* __restrict__ lnb, int N)
{
    const int lane = threadIdx.x & 63;
    const int wid  = threadIdx.x >> 6;
    const int lr   = lane & 15;        // frag row (A) / col (B/C)
    const int kb   = lane >> 4;        // k-block 0..3
    const int row0 = blockIdx.x * 128 + wid * 32;

    v4f acc[2][8] = {};

#pragma unroll
    for (int mat = 0; mat < 2; ++mat) {
        const float* Asrc = mat ? xC : buf;
        const uint4* BH = (const uint4*)(mat ? wch : wlh);
        const uint4* BL = (const uint4*)(mat ? wcl : wll);
#pragma unroll
        for (int kc = 0; kc < 4; ++kc) {
            Frag ah[2], al[2];
#pragma unroll
            for (int rt = 0; rt < 2; ++rt) {
                int r = row0 + rt * 16 + lr;
                r = (r < N) ? r : (N - 1);
                const float4* ap = (const float4*)(
                    Asrc + (size_t)r * HD + kc * 32 + kb * 8);
                float4 u0 = ap[0], u1 = ap[1];
                float f[8] = {u0.x, u0.y, u0.z, u0.w, u1.x, u1.y, u1.z, u1.w};
                cvt_split8(f, ah[rt].u, al[rt].u);
            }
#pragma unroll
            for (int ct = 0; ct < 8; ++ct) {
                int idx = kc * 512 + (ct * 16 + lr) * 4 + kb;
                Frag bh, bl;
                bh.q = BH[idx];
                bl.q = BL[idx];
#pragma unroll
                for (int rt = 0; rt < 2; ++rt) {
                    acc[rt][ct] = __builtin_amdgcn_mfma_f32_16x16x32_bf16(
                        ah[rt].v, bh.v, acc[rt][ct], 0, 0, 0);
                    acc[rt][ct] = __builtin_amdgcn_mfma_f32_16x16x32_bf16(
                        ah[rt].v, bl.v, acc[rt][ct], 0, 0, 0);
                    acc[rt][ct] = __builtin_amdgcn_mfma_f32_16x16x32_bf16(
                        al[rt].v, bh.v, acc[rt][ct], 0, 0, 0);
                }
            }
        }
    }

    // ---- epilogue: bias, relu, LN (shfl over the 16-lane group), select
    float bcv[8], gav[8], bev[8];
#pragma unroll
    for (int ct = 0; ct < 8; ++ct) {
        int c = ct * 16 + lr;
        bcv[ct] = bc[c];
        gav[ct] = lng[c];
        bev[ct] = lnb[c];
    }

#pragma unroll
    for (int rt = 0; rt < 2; ++rt) {
        int rq = row0 + rt * 16 + kb * 4;    // first of this lane's 4 rows
        int cvr[4] = {0, 0, 0, 0};
        if (rq < N) {                        // N % 4 == 0, rq % 4 == 0
            int4 cv = *(const int4*)(cnt + rq);
            cvr[0] = cv.x; cvr[1] = cv.y; cvr[2] = cv.z; cvr[3] = cv.w;
        }
#pragma unroll
        for (int reg = 0; reg < 4; ++reg) {
            float yv[8];
            float s = 0.f, q = 0.f;
#pragma unroll
            for (int ct = 0; ct < 8; ++ct) {
                float v = acc[rt][ct][reg] + bcv[ct];
                v = fmaxf(v, 0.0f);
                yv[ct] = v;
                s += v;
                q += v * v;
            }
#pragma unroll
            for (int m = 1; m < 16; m <<= 1) {
                s += __shfl_xor(s, m);
                q += __shfl_xor(q, m);
            }
            float mu   = s * (1.0f / 128.0f);
            float var  = q * (1.0f / 128.0f) - mu * mu;
            float rstd = rsqrtf(var + 1e-5f);

            int r = rq + reg;
            if (r < N) {
                size_t base = (size_t)r * HD;
                if (cvr[reg] > 0) {
#pragma unroll
                    for (int ct = 0; ct < 8; ++ct)
                        buf[base + ct * 16 + lr] =
                            (yv[ct] - mu) * rstd * gav[ct] + bev[ct];
                } else {
#pragma unroll
                    for (int ct = 0; ct < 8; ++ct)
                        buf[base + ct * 16 + lr] = xC[base + ct * 16 + lr];
                }
            }
        }
    }
}

// ---------------------------------------------------------------- K3: MFMA out
// wave owns 32 rows x 64 cols (2 row-tiles x 4 col-tiles).  K=128.
__global__ __launch_bounds__(256) void k_out_mfma(
    const float* __restrict__ hC, const u16* __restrict__ woh,
    const u16* __restrict__ wol, const float* __restrict__ bout,
    float* __restrict__ out, int N)
{
    const int lane = threadIdx.x & 63;
    const int wid  = threadIdx.x >> 6;
    const int lr   = lane & 15;
    const int kb   = lane >> 4;
    const int row0 = blockIdx.x * 128 + wid * 32;

    v4f acc[2][4] = {};
    const uint4* BH = (const uint4*)woh;
    const uint4* BL = (const uint4*)wol;

#pragma unroll
    for (int kc = 0; kc < 4; ++kc) {
        Frag ah[2], al[2];
#pragma unroll
        for (int rt = 0; rt < 2; ++rt) {
            int r = row0 + rt * 16 + lr;
            r = (r < N) ? r : (N - 1);
            const float4* ap = (const float4*)(
                hC + (size_t)r * HD + kc * 32 + kb * 8);
            float4 u0 = ap[0], u1 = ap[1];
            float f[8] = {u0.x, u0.y, u0.z, u0.w, u1.x, u1.y, u1.z, u1.w};
            cvt_split8(f, ah[rt].u, al[rt].u);
        }
#pragma unroll
        for (int ct = 0; ct < 4; ++ct) {
            int idx = kc * 256 + (ct * 16 + lr) * 4 + kb;
            Frag bh, bl;
            bh.q = BH[idx];
            bl.q = BL[idx];
#pragma unroll
            for (int rt = 0; rt < 2; ++rt) {
                acc[rt][ct] = __builtin_amdgcn_mfma_f32_16x16x32_bf16(
                    ah[rt].v, bh.v, acc[rt][ct], 0, 0, 0);
                acc[rt][ct] = __builtin_amdgcn_mfma_f32_16x16x32_bf16(
                    ah[rt].v, bl.v, acc[rt][ct], 0, 0, 0);
                acc[rt][ct] = __builtin_amdgcn_mfma_f32_16x16x32_bf16(
                    al[rt].v, bh.v, acc[rt][ct], 0, 0, 0);
            }
        }
    }

    float bov[4];
#pragma unroll
    for (int ct = 0; ct < 4; ++ct) bov[ct] = bout[ct * 16 + lr];

#pragma unroll
    for (int rt = 0; rt < 2; ++rt) {
#pragma unroll
        for (int reg = 0; reg < 4; ++reg) {
            int r = row0 + rt * 16 + kb * 4 + reg;
            if (r < N) {
#pragma unroll
                for (int ct = 0; ct < 4; ++ct)
                    out[(size_t)r * OD + ct * 16 + lr] =
                        acc[rt][ct][reg] + bov[ct];
            }
        }
    }
}

// ---------------------------------------------------------------- launch
extern "C" void kernel_launch(void* const* d_in, const int* in_sizes, int n_in,
                              void* d_out, int out_size, void* d_ws, size_t ws_size,
                              hipStream_t stream) {
    const float* xB    = (const float*)d_in[1];
    const float* xC    = (const float*)d_in[2];
    const float* tB    = (const float*)d_in[4];
    const float* tC    = (const float*)d_in[5];
    const int*   edge2 = (const int*)d_in[7];
    const float* Wl1   = (const float*)d_in[18];
    const float* bl1   = (const float*)d_in[19];
    const float* W01   = (const float*)d_in[20];
    const float* b01   = (const float*)d_in[21];
    const float* W11   = (const float*)d_in[22];
    const float* b11   = (const float*)d_in[23];
    const float* gate1 = (const float*)d_in[24];
    const float* lam1  = (const float*)d_in[25];
    const float* lng1  = (const float*)d_in[26];
    const float* lnb1  = (const float*)d_in[27];
    const float* Wout  = (const float*)d_in[28];
    const float* bout  = (const float*)d_in[29];

    const int N = in_sizes[2] / HD;
    const int E = in_sizes[7] / 2;

    int*   cnt   = (int*)d_ws;
    int*   fillc = cnt + N;
    int*   offs  = fillc + N;
    int*   part  = offs + N;
    int2*  srcw  = (int2*)(part + 128);
    u16*   wlh   = (u16*)(srcw + E);
    u16*   wll   = wlh + 16384;
    u16*   wch   = wll + 16384;
    u16*   wcl   = wch + 16384;
    u16*   woh   = wcl + 16384;
    u16*   wol   = woh + 8192;
    float* bc    = (float*)(wol + 8192);
    float* buf   = bc + 128;             // agg_norm, then hC in-place

    hipMemsetAsync(cnt, 0, (size_t)2 * N * sizeof(int), stream);

    dim3 blk(256);
    const int gE = (E + 255) / 256;
    const int NB = (N + SCAN_E - 1) / SCAN_E;

    k_wprep<<<97, blk, 0, stream>>>(Wl1, W01, W11, Wout, bl1, b01, b11, gate1,
                                    wlh, wll, wch, wcl, woh, wol, bc);
    k_hist <<<gE, blk, 0, stream>>>(edge2, cnt, E);
    k_scan1<<<NB, blk, 0, stream>>>(cnt, offs, part, N);
    k_scan2<<<1, 128, 0, stream>>>(part, NB);
    k_fillw<<<gE, blk, 0, stream>>>(edge2, tB, tC, lam1, offs, part, fillc, srcw, E);

    const int gN64 = (N * 64 + 255) / 256;
    k_gather<<<gN64, blk, 0, stream>>>(xB, srcw, offs, part, cnt, buf, N);

    const int GB = (N + 127) / 128;
    k_layer_mfma<<<GB, blk, 0, stream>>>(xC, buf, cnt, wlh, wll, wch, wcl,
                                         bc, lng1, lnb1, N);
    k_out_mfma  <<<GB, blk, 0, stream>>>(buf, woh, wol, bout, (float*)d_out, N);
}

// Round 10
// 220.433 us; speedup vs baseline: 7.1001x; 1.0754x over previous
//
#include <hip/hip_runtime.h>

// MetaPathGNN — only the edge2 (B->C) layer + output GEMM matter
// (h_B is dead code in the reference).
//
// R10: fuse K2+K3 (hC lives in swizzled LDS, never hits global); gather with
// 4-way edge ILP.  R9 counters: k_layer latency-bound (Mfma 10%, VALU 11%,
// occ 15.5%), k_out repeated the pattern + 102MB hC round-trip.
//   memset : zero cnt|fillc (2N ints)
//   K_hist/scan1/scan2/fillw : CSR with precomputed edge weights
//   K_wprep: split Wl, Wc=(1-g)W0+gW1, Wout into transposed packed bf16
//            hi/lo planes [kc][n][ks=32]; bc = bl+(1-g)b0+g*b1
//   K_gather: wave per node, 4 edge slots x 16 lanes: aggn = sum w*xB / sum w
//   K_fused: K2 (agg@Wl + xC@Wc -> relu,LN,select) -> per-wave LDS slice
//            K3 (hC @ Wout + bout) -> d_out.  Zero-LDS-conflict via XOR swz.
//
// ws (4B units): [cnt N | fillc N | offs N | part 128 | srcw 2E |
//                 wlh/wll/wch/wcl 16384ush | woh/wol 8192ush | bc 128 | buf N*128]

#define HD 128
#define OD 64
#define SCAN_E 1024

typedef unsigned short u16;
typedef short v8s __attribute__((ext_vector_type(8)));
typedef float v4f __attribute__((ext_vector_type(4)));

union Frag {
    unsigned int u[4];
    uint4 q;
    v8s v;
};

__device__ __forceinline__ float softplus_f(float x) {
    return fmaxf(x, 0.0f) + log1pf(expf(-fabsf(x)));
}
__device__ __forceinline__ float sigmoid_f(float x) {
    return 1.0f / (1.0f + expf(-x));
}
// swizzled LDS offset within a [32][128] fp32 slice: granule XOR row&7
__device__ __forceinline__ int swz(int r, int c) {
    int g = (c >> 2) ^ (r & 7);
    return r * 128 + g * 4 + (c & 3);
}

// split x into bf16 hi + bf16 lo (truncation split; residual ~2^-17 |x|)
__device__ __forceinline__ void split_store(float x, u16* ph, u16* pl) {
    unsigned int b = __float_as_uint(x);
    unsigned int h = b & 0xffff0000u;
    *ph = (u16)(h >> 16);
    float r = x - __uint_as_float(h);
    *pl = (u16)(__float_as_uint(r) >> 16);
}

// 8 floats -> 4 packed dwords hi, 4 packed dwords lo (2 bf16 per dword)
__device__ __forceinline__ void cvt_split8(const float* f, unsigned int* hi,
                                           unsigned int* lo) {
#pragma unroll
    for (int j = 0; j < 4; ++j) {
        unsigned int b0 = __float_as_uint(f[2 * j]);
        unsigned int b1 = __float_as_uint(f[2 * j + 1]);
        unsigned int h0 = b0 & 0xffff0000u;
        unsigned int h1 = b1 & 0xffff0000u;
        hi[j] = (h0 >> 16) | h1;
        float r0 = f[2 * j]     - __uint_as_float(h0);
        float r1 = f[2 * j + 1] - __uint_as_float(h1);
        lo[j] = (__float_as_uint(r0) >> 16) | (__float_as_uint(r1) & 0xffff0000u);
    }
}

// ---------------------------------------------------------------- histogram
__global__ __launch_bounds__(256) void k_hist(
    const int* __restrict__ edge, int* __restrict__ cnt, int E)
{
    int e = blockIdx.x * 256 + threadIdx.x;
    if (e < E) atomicAdd(cnt + edge[E + e], 1);
}

// ---------------------------------------------------------------- scan (2-level)
__global__ __launch_bounds__(256) void k_scan1(
    const int* __restrict__ cnt, int* __restrict__ offs,
    int* __restrict__ part, int N)
{
    __shared__ int sh[256];
    const int t = threadIdx.x;
    const int base = blockIdx.x * SCAN_E + t * 4;
    int v[4], sum = 0;
#pragma unroll
    for (int i = 0; i < 4; ++i) {
        int idx = base + i;
        v[i] = (idx < N) ? cnt[idx] : 0;
        sum += v[i];
    }
    sh[t] = sum;
    __syncthreads();
    for (int off = 1; off < 256; off <<= 1) {
        int x = (t >= off) ? sh[t - off] : 0;
        __syncthreads();
        sh[t] += x;
        __syncthreads();
    }
    int run = (t > 0) ? sh[t - 1] : 0;
    if (t == 255) part[blockIdx.x] = sh[t];
#pragma unroll
    for (int i = 0; i < 4; ++i) {
        int idx = base + i;
        if (idx < N) offs[idx] = run;
        run += v[i];
    }
}

__global__ __launch_bounds__(128) void k_scan2(int* __restrict__ part, int NB)
{
    __shared__ int sh[128];
    const int t = threadIdx.x;
    sh[t] = (t < NB) ? part[t] : 0;
    __syncthreads();
    for (int off = 1; off < 128; off <<= 1) {
        int x = (t >= off) ? sh[t - off] : 0;
        __syncthreads();
        sh[t] += x;
        __syncthreads();
    }
    if (t < NB) part[t] = (t > 0) ? sh[t - 1] : 0;
}

// ---------------------------------------------------------------- CSR fill + weight
__global__ __launch_bounds__(256) void k_fillw(
    const int* __restrict__ edge, const float* __restrict__ tB,
    const float* __restrict__ tC, const float* __restrict__ lam_raw,
    const int* __restrict__ offs, const int* __restrict__ part,
    int* __restrict__ fillc, int2* __restrict__ srcw, int E)
{
    int e = blockIdx.x * 256 + threadIdx.x;
    if (e >= E) return;
    int s = edge[e];
    int d = edge[E + e];
    float lam = softplus_f(lam_raw[0]) + 1e-8f;
    float dt  = fmaxf(tC[d] - tB[s], 0.0f);
    float w   = expf(fmaxf(-lam * dt, -60.0f));
    int pos = offs[d] + part[d >> 10] + atomicAdd(fillc + d, 1);
    srcw[pos] = make_int2(s, __float_as_int(w));
}

// ---------------------------------------------------------------- weight prep
__global__ __launch_bounds__(256) void k_wprep(
    const float* __restrict__ Wl, const float* __restrict__ W0,
    const float* __restrict__ W1, const float* __restrict__ Wout,
    const float* __restrict__ bl, const float* __restrict__ b0,
    const float* __restrict__ b1, const float* __restrict__ gatep,
    u16* __restrict__ wlh, u16* __restrict__ wll,
    u16* __restrict__ wch, u16* __restrict__ wcl,
    u16* __restrict__ woh, u16* __restrict__ wol, float* __restrict__ bc)
{
    int i = blockIdx.x * 256 + threadIdx.x;
    const float g = sigmoid_f(gatep[0]);
    if (i < 16384) {
        int n = i >> 7, k = i & 127;
        float a  = Wl[k * 128 + n];
        float w0 = W0[k * 128 + n];
        float w1 = W1[k * 128 + n];
        float c  = (1.f - g) * w0 + g * w1;
        int off = ((k >> 5) * 128 + n) * 32 + (k & 31);
        split_store(a, wlh + off, wll + off);
        split_store(c, wch + off, wcl + off);
    } else if (i < 24576) {
        int j = i - 16384;
        int n = j >> 7, k = j & 127;          // n 0..63, k 0..127
        float v = Wout[k * 64 + n];
        int off = ((k >> 5) * 64 + n) * 32 + (k & 31);
        split_store(v, woh + off, wol + off);
    } else if (i < 24704) {
        int t = i - 24576;
        bc[t] = bl[t] + (1.f - g) * b0[t] + g * b1[t];
    }
}

// ---------------------------------------------------------------- gather
// wave per node; 4 edge slots x 16 lanes; lane covers cols [l4*4) and [64+l4*4)
__global__ __launch_bounds__(256) void k_gather(
    const float* __restrict__ xB, const int2* __restrict__ srcw,
    const int* __restrict__ offs, const int* __restrict__ part,
    const int* __restrict__ cnt, float* __restrict__ aggn, int N)
{
    const int wave = (blockIdx.x * 256 + threadIdx.x) >> 6;
    const int lane = threadIdx.x & 63;
    const int slot = lane >> 4;
    const int l4   = lane & 15;
    if (wave >= N) return;
    const int r    = wave;
    const int degc = cnt[r];

    float* dstp = aggn + (size_t)r * HD;
    if (degc == 0) {
        if (slot == 0) {
            *reinterpret_cast<float4*>(dstp + l4 * 4) = make_float4(0, 0, 0, 0);
            *reinterpret_cast<float4*>(dstp + 64 + l4 * 4) = make_float4(0, 0, 0, 0);
        }
        return;
    }

    const int start = offs[r] + part[r >> 10];
    float4 a0 = make_float4(0, 0, 0, 0), a1 = make_float4(0, 0, 0, 0);
    float sw = 0.f;
    for (int j = slot; j < degc; j += 4) {
        int2 swp = srcw[start + j];
        float w = __int_as_float(swp.y);
        const float* row = xB + (size_t)swp.x * HD;
        float4 x0 = *reinterpret_cast<const float4*>(row + l4 * 4);
        float4 x1 = *reinterpret_cast<const float4*>(row + 64 + l4 * 4);
        a0.x = fmaf(w, x0.x, a0.x); a0.y = fmaf(w, x0.y, a0.y);
        a0.z = fmaf(w, x0.z, a0.z); a0.w = fmaf(w, x0.w, a0.w);
        a1.x = fmaf(w, x1.x, a1.x); a1.y = fmaf(w, x1.y, a1.y);
        a1.z = fmaf(w, x1.z, a1.z); a1.w = fmaf(w, x1.w, a1.w);
        sw += w;
    }
#pragma unroll
    for (int m = 16; m <= 32; m <<= 1) {
        a0.x += __shfl_xor(a0.x, m); a0.y += __shfl_xor(a0.y, m);
        a0.z += __shfl_xor(a0.z, m); a0.w += __shfl_xor(a0.w, m);
        a1.x += __shfl_xor(a1.x, m); a1.y += __shfl_xor(a1.y, m);
        a1.z += __shfl_xor(a1.z, m); a1.w += __shfl_xor(a1.w, m);
        sw   += __shfl_xor(sw, m);
    }
    float inv = 1.0f / fmaxf(sw, 1e-6f);
    if (slot == 0) {
        a0.x *= inv; a0.y *= inv; a0.z *= inv; a0.w *= inv;
        a1.x *= inv; a1.y *= inv; a1.z *= inv; a1.w *= inv;
        *reinterpret_cast<float4*>(dstp + l4 * 4) = a0;
        *reinterpret_cast<float4*>(dstp + 64 + l4 * 4) = a1;
    }
}

// ---------------------------------------------------------------- fused K2+K3
// block = 256 thr = 4 waves; wave owns 32 rows.  K2: acc[2][8] over K=256
// (agg@Wl then xC@Wc), epilogue (bias,relu,LN,select) -> per-wave 16KB LDS
// slice (XOR-swizzled).  K3: hC(LDS) @ Wout + bout -> d_out.  No hC in global.
__global__ __launch_bounds__(256) void k_fused(
    const float* __restrict__ xC, const float* __restrict__ aggn,
    const int* __restrict__ cnt,
    const u16* __restrict__ wlh, const u16* __restrict__ wll,
    const u16* __restrict__ wch, const u16* __restrict__ wcl,
    const u16* __restrict__ woh, const u16* __restrict__ wol,
    const float* __restrict__ bc, const float* __restrict__ lng,
    const float* __restrict__ lnb, const float* __restrict__ bout,
    float* __restrict__ out, int N)
{
    __shared__ float lds[4 * 32 * 128];     // 64 KB, per-wave 16KB slices

    const int lane = threadIdx.x & 63;
    const int wid  = threadIdx.x >> 6;
    const int lr   = lane & 15;        // frag row (A) / col (B/C)
    const int kb   = lane >> 4;        // k-block 0..3
    const int row0 = blockIdx.x * 128 + wid * 32;
    float* myl = lds + wid * 32 * 128;

    // ================= K2 =================
    v4f acc[2][8] = {};

#pragma unroll
    for (int mat = 0; mat < 2; ++mat) {
        const float* Asrc = mat ? xC : aggn;
        const uint4* BH = (const uint4*)(mat ? wch : wlh);
        const uint4* BL = (const uint4*)(mat ? wcl : wll);
#pragma unroll
        for (int kc = 0; kc < 4; ++kc) {
            Frag ah[2], al[2];
#pragma unroll
            for (int rt = 0; rt < 2; ++rt) {
                int r = row0 + rt * 16 + lr;
                r = (r < N) ? r : (N - 1);
                const float4* ap = (const float4*)(
                    Asrc + (size_t)r * HD + kc * 32 + kb * 8);
                float4 u0 = ap[0], u1 = ap[1];
                float f[8] = {u0.x, u0.y, u0.z, u0.w, u1.x, u1.y, u1.z, u1.w};
                cvt_split8(f, ah[rt].u, al[rt].u);
            }
#pragma unroll
            for (int ct = 0; ct < 8; ++ct) {
                int idx = kc * 512 + (ct * 16 + lr) * 4 + kb;
                Frag bh, bl;
                bh.q = BH[idx];
                bl.q = BL[idx];
#pragma unroll
                for (int rt = 0; rt < 2; ++rt) {
                    acc[rt][ct] = __builtin_amdgcn_mfma_f32_16x16x32_bf16(
                        ah[rt].v, bh.v, acc[rt][ct], 0, 0, 0);
                    acc[rt][ct] = __builtin_amdgcn_mfma_f32_16x16x32_bf16(
                        ah[rt].v, bl.v, acc[rt][ct], 0, 0, 0);
                    acc[rt][ct] = __builtin_amdgcn_mfma_f32_16x16x32_bf16(
                        al[rt].v, bh.v, acc[rt][ct], 0, 0, 0);
                }
            }
        }
    }

    // ---- epilogue: bias, relu, LN (shfl over 16-lane group), select -> LDS
    float bcv[8], gav[8], bev[8];
#pragma unroll
    for (int ct = 0; ct < 8; ++ct) {
        int c = ct * 16 + lr;
        bcv[ct] = bc[c];
        gav[ct] = lng[c];
        bev[ct] = lnb[c];
    }

#pragma unroll
    for (int rt = 0; rt < 2; ++rt) {
        int rq = row0 + rt * 16 + kb * 4;    // first of this lane's 4 rows
        int cvr[4] = {0, 0, 0, 0};
        if (rq < N) {                        // N%4==0, rq%4==0 -> rq+3 < N
            int4 cv = *(const int4*)(cnt + rq);
            cvr[0] = cv.x; cvr[1] = cv.y; cvr[2] = cv.z; cvr[3] = cv.w;
        }
#pragma unroll
        for (int reg = 0; reg < 4; ++reg) {
            int rloc = rt * 16 + kb * 4 + reg;
            int r    = rq + reg;
            float yv[8];
            float s = 0.f, q = 0.f;
#pragma unroll
            for (int ct = 0; ct < 8; ++ct) {
                float v = acc[rt][ct][reg] + bcv[ct];
                v = fmaxf(v, 0.0f);
                yv[ct] = v;
                s += v;
                q += v * v;
            }
#pragma unroll
            for (int m = 1; m < 16; m <<= 1) {
                s += __shfl_xor(s, m);
                q += __shfl_xor(q, m);
            }
            float mu   = s * (1.0f / 128.0f);
            float var  = q * (1.0f / 128.0f) - mu * mu;
            float rstd = rsqrtf(var + 1e-5f);

            if (r < N) {
                if (cvr[reg] > 0) {
#pragma unroll
                    for (int ct = 0; ct < 8; ++ct)
                        myl[swz(rloc, ct * 16 + lr)] =
                            (yv[ct] - mu) * rstd * gav[ct] + bev[ct];
                } else {
                    size_t base = (size_t)r * HD;
#pragma unroll
                    for (int ct = 0; ct < 8; ++ct)
                        myl[swz(rloc, ct * 16 + lr)] = xC[base + ct * 16 + lr];
                }
            } else {
#pragma unroll
                for (int ct = 0; ct < 8; ++ct)
                    myl[swz(rloc, ct * 16 + lr)] = 0.0f;
            }
        }
    }

    __syncthreads();   // order LDS writes before K3 reads (wave-local, but safe)

    // ================= K3 =================
    v4f acc2[2][4] = {};
    const uint4* BH = (const uint4*)woh;
    const uint4* BL = (const uint4*)wol;

#pragma unroll
    for (int kc = 0; kc < 4; ++kc) {
        Frag ah[2], al[2];
#pragma unroll
        for (int rt = 0; rt < 2; ++rt) {
            int rloc = rt * 16 + lr;
            int c0   = kc * 32 + kb * 8;
            float4 u0 = *reinterpret_cast<const float4*>(&myl[swz(rloc, c0)]);
            float4 u1 = *reinterpret_cast<const float4*>(&myl[swz(rloc, c0 + 4)]);
            float f[8] = {u0.x, u0.y, u0.z, u0.w, u1.x, u1.y, u1.z, u1.w};
            cvt_split8(f, ah[rt].u, al[rt].u);
        }
#pragma unroll
        for (int ct = 0; ct < 4; ++ct) {
            int idx = kc * 256 + (ct * 16 + lr) * 4 + kb;
            Frag bh, bl;
            bh.q = BH[idx];
            bl.q = BL[idx];
#pragma unroll
            for (int rt = 0; rt < 2; ++rt) {
                acc2[rt][ct] = __builtin_amdgcn_mfma_f32_16x16x32_bf16(
                    ah[rt].v, bh.v, acc2[rt][ct], 0, 0, 0);
                acc2[rt][ct] = __builtin_amdgcn_mfma_f32_16x16x32_bf16(
                    ah[rt].v, bl.v, acc2[rt][ct], 0, 0, 0);
                acc2[rt][ct] = __builtin_amdgcn_mfma_f32_16x16x32_bf16(
                    al[rt].v, bh.v, acc2[rt][ct], 0, 0, 0);
            }
        }
    }

    float bov[4];
#pragma unroll
    for (int ct = 0; ct < 4; ++ct) bov[ct] = bout[ct * 16 + lr];

#pragma unroll
    for (int rt = 0; rt < 2; ++rt) {
#pragma unroll
        for (int reg = 0; reg < 4; ++reg) {
            int r = row0 + rt * 16 + kb * 4 + reg;
            if (r < N) {
#pragma unroll
                for (int ct = 0; ct < 4; ++ct)
                    out[(size_t)r * OD + ct * 16 + lr] =
                        acc2[rt][ct][reg] + bov[ct];
            }
        }
    }
}

// ---------------------------------------------------------------- launch
extern "C" void kernel_launch(void* const* d_in, const int* in_sizes, int n_in,
                              void* d_out, int out_size, void* d_ws, size_t ws_size,
                              hipStream_t stream) {
    const float* xB    = (const float*)d_in[1];
    const float* xC    = (const float*)d_in[2];
    const float* tB    = (const float*)d_in[4];
    const float* tC    = (const float*)d_in[5];
    const int*   edge2 = (const int*)d_in[7];
    const float* Wl1   = (const float*)d_in[18];
    const float* bl1   = (const float*)d_in[19];
    const float* W01   = (const float*)d_in[20];
    const float* b01   = (const float*)d_in[21];
    const float* W11   = (const float*)d_in[22];
    const float* b11   = (const float*)d_in[23];
    const float* gate1 = (const float*)d_in[24];
    const float* lam1  = (const float*)d_in[25];
    const float* lng1  = (const float*)d_in[26];
    const float* lnb1  = (const float*)d_in[27];
    const float* Wout  = (const float*)d_in[28];
    const float* bout  = (const float*)d_in[29];

    const int N = in_sizes[2] / HD;
    const int E = in_sizes[7] / 2;

    int*   cnt   = (int*)d_ws;
    int*   fillc = cnt + N;
    int*   offs  = fillc + N;
    int*   part  = offs + N;
    int2*  srcw  = (int2*)(part + 128);
    u16*   wlh   = (u16*)(srcw + E);
    u16*   wll   = wlh + 16384;
    u16*   wch   = wll + 16384;
    u16*   wcl   = wch + 16384;
    u16*   woh   = wcl + 16384;
    u16*   wol   = woh + 8192;
    float* bc    = (float*)(wol + 8192);
    float* buf   = bc + 128;             // agg_norm

    hipMemsetAsync(cnt, 0, (size_t)2 * N * sizeof(int), stream);

    dim3 blk(256);
    const int gE = (E + 255) / 256;
    const int NB = (N + SCAN_E - 1) / SCAN_E;

    k_wprep<<<97, blk, 0, stream>>>(Wl1, W01, W11, Wout, bl1, b01, b11, gate1,
                                    wlh, wll, wch, wcl, woh, wol, bc);
    k_hist <<<gE, blk, 0, stream>>>(edge2, cnt, E);
    k_scan1<<<NB, blk, 0, stream>>>(cnt, offs, part, N);
    k_scan2<<<1, 128, 0, stream>>>(part, NB);
    k_fillw<<<gE, blk, 0, stream>>>(edge2, tB, tC, lam1, offs, part, fillc, srcw, E);

    const int gN64 = (N * 64 + 255) / 256;
    k_gather<<<gN64, blk, 0, stream>>>(xB, srcw, offs, part, cnt, buf, N);

    const int GB = (N + 127) / 128;
    k_fused<<<GB, blk, 0, stream>>>(xC, buf, cnt, wlh, wll, wch, wcl, woh, wol,
                                    bc, lng1, lnb1, bout, (float*)d_out, N);
}